// Round 1
// baseline (89.427 us; speedup 1.0000x reference)
//
#include <hip/hip_runtime.h>
#include <hip/hip_bf16.h>
#include <stdint.h>

#define N 4096
#define D 512
#define TILE 128
#define BK 32
#define NB (N / TILE)  // 32

typedef __bf16 bf16x8 __attribute__((ext_vector_type(8)));
typedef float f32x4 __attribute__((ext_vector_type(4)));

// ---------------------------------------------------------------------------
// Kernel 1: fp32 -> bf16 conversion (for MFMA) + fp32 row squared-norms.
// One wave per row: 512 elems / 64 lanes = 8 elems/lane (one 16B bf16 store).
// ---------------------------------------------------------------------------
__global__ __launch_bounds__(256) void prep_kernel(const float* __restrict__ x,
                                                   __bf16* __restrict__ xb,
                                                   float* __restrict__ sq) {
    int row  = blockIdx.x * 4 + (threadIdx.x >> 6);
    int lane = threadIdx.x & 63;
    const float* xr = x + (size_t)row * D + lane * 8;
    float4 v0 = *reinterpret_cast<const float4*>(xr);
    float4 v1 = *reinterpret_cast<const float4*>(xr + 4);

    bf16x8 b;
    b[0] = (__bf16)v0.x; b[1] = (__bf16)v0.y; b[2] = (__bf16)v0.z; b[3] = (__bf16)v0.w;
    b[4] = (__bf16)v1.x; b[5] = (__bf16)v1.y; b[6] = (__bf16)v1.z; b[7] = (__bf16)v1.w;
    *reinterpret_cast<bf16x8*>(xb + (size_t)row * D + lane * 8) = b;

    float s = v0.x * v0.x + v0.y * v0.y + v0.z * v0.z + v0.w * v0.w +
              v1.x * v1.x + v1.y * v1.y + v1.z * v1.z + v1.w * v1.w;
    #pragma unroll
    for (int off = 32; off > 0; off >>= 1) s += __shfl_down(s, off);
    if (lane == 0) sq[row] = s;
}

// ---------------------------------------------------------------------------
// Kernel 2: lower-triangle Gram via bf16 MFMA (m97 structure) + fused
// distance epilogue. 256 threads = 4 waves in 2x2; each wave owns 64x64.
// ---------------------------------------------------------------------------
__global__ __launch_bounds__(256) void pairdist_kernel(const __bf16* __restrict__ xb,
                                                       const float* __restrict__ sq,
                                                       float* __restrict__ out) {
    __shared__ __bf16 As[TILE * BK];  // 8 KB, row-major [row][k], stride 32 (no pad: global_load_lds)
    __shared__ __bf16 Bs[TILE * BK];  // 8 KB

    // Linear block id -> (bi, bj) with bj <= bi (lower-triangular block pairs)
    int t  = blockIdx.x;
    int bi = (int)((sqrtf(8.0f * (float)t + 1.0f) - 1.0f) * 0.5f);
    while ((bi + 1) * (bi + 2) / 2 <= t) bi++;
    while (bi * (bi + 1) / 2 > t) bi--;
    int bj = t - bi * (bi + 1) / 2;

    int tid  = threadIdx.x;
    int w    = tid >> 6;        // wave 0..3
    int lane = tid & 63;
    int quad = lane >> 4;       // 0..3
    int lr   = lane & 15;       // 0..15
    int wm   = w >> 1;          // wave row (0..1) -> 64 rows
    int wn   = w & 1;           // wave col (0..1) -> 64 cols

    f32x4 acc[4][4];
    #pragma unroll
    for (int mt = 0; mt < 4; mt++)
        #pragma unroll
        for (int nt = 0; nt < 4; nt++)
            acc[mt][nt] = (f32x4)0.0f;

    // Staging: per global_load_lds issue, each wave loads 16 rows x 64B.
    // lane l -> row l/4, byte (l%4)*16 within the 64B row slice; the HW LDS
    // placement base + lane*16 matches As[row][k] with stride 64B exactly.
    int srow = lane >> 2;            // 0..15
    int scol = (lane & 3) * 8;       // bf16 elems within 32
    const __bf16* ga = xb + (size_t)(bi * TILE + w * 16 + srow) * D + scol;
    const __bf16* gb = xb + (size_t)(bj * TILE + w * 16 + srow) * D + scol;
    __bf16* la = As + w * 16 * BK;   // wave-uniform LDS bases
    __bf16* lb = Bs + w * 16 * BK;

    for (int k0 = 0; k0 < D; k0 += BK) {
        __syncthreads();
        __builtin_amdgcn_global_load_lds(
            (const __attribute__((address_space(1))) void*)(ga + k0),
            (__attribute__((address_space(3))) void*)la, 16, 0, 0);
        __builtin_amdgcn_global_load_lds(
            (const __attribute__((address_space(1))) void*)(ga + k0 + (size_t)64 * D),
            (__attribute__((address_space(3))) void*)(la + 64 * BK), 16, 0, 0);
        __builtin_amdgcn_global_load_lds(
            (const __attribute__((address_space(1))) void*)(gb + k0),
            (__attribute__((address_space(3))) void*)lb, 16, 0, 0);
        __builtin_amdgcn_global_load_lds(
            (const __attribute__((address_space(1))) void*)(gb + k0 + (size_t)64 * D),
            (__attribute__((address_space(3))) void*)(lb + 64 * BK), 16, 0, 0);
        __syncthreads();

        // Fragment loads: A[m = lr][k = quad*8 + j], B[n = lr][k = quad*8 + j]
        bf16x8 af[4], bfr[4];
        #pragma unroll
        for (int mt = 0; mt < 4; mt++)
            af[mt] = *reinterpret_cast<const bf16x8*>(
                As + (wm * 64 + mt * 16 + lr) * BK + quad * 8);
        #pragma unroll
        for (int nt = 0; nt < 4; nt++)
            bfr[nt] = *reinterpret_cast<const bf16x8*>(
                Bs + (wn * 64 + nt * 16 + lr) * BK + quad * 8);

        #pragma unroll
        for (int mt = 0; mt < 4; mt++)
            #pragma unroll
            for (int nt = 0; nt < 4; nt++)
                acc[mt][nt] = __builtin_amdgcn_mfma_f32_16x16x32_bf16(
                    af[mt], bfr[nt], acc[mt][nt], 0, 0, 0);
    }

    // Epilogue: D[m][n] at lane: n = lane&15, m = quad*4 + reg  (verified m89/m91)
    int ibase = bi * TILE + wm * 64;
    int jbase = bj * TILE + wn * 64;

    float sqi[4][4], sqj[4];
    #pragma unroll
    for (int mt = 0; mt < 4; mt++)
        #pragma unroll
        for (int tt = 0; tt < 4; tt++)
            sqi[mt][tt] = sq[ibase + mt * 16 + quad * 4 + tt];
    #pragma unroll
    for (int nt = 0; nt < 4; nt++)
        sqj[nt] = sq[jbase + nt * 16 + lr];

    #pragma unroll
    for (int mt = 0; mt < 4; mt++) {
        #pragma unroll
        for (int tt = 0; tt < 4; tt++) {
            int i = ibase + mt * 16 + quad * 4 + tt;
            unsigned rowoff = (unsigned)(i * (i - 1) / 2);
            #pragma unroll
            for (int nt = 0; nt < 4; nt++) {
                int j = jbase + nt * 16 + lr;
                if (j < i) {
                    float d2 = sqi[mt][tt] + sqj[nt] - 2.0f * acc[mt][nt][tt];
                    out[rowoff + (unsigned)j] = sqrtf(fmaxf(d2, 0.0f));
                }
            }
        }
    }
}

extern "C" void kernel_launch(void* const* d_in, const int* in_sizes, int n_in,
                              void* d_out, int out_size, void* d_ws, size_t ws_size,
                              hipStream_t stream) {
    const float* x = (const float*)d_in[0];
    float* out = (float*)d_out;

    // Workspace layout: [0, 4MB) bf16 copy of x; then 16KB of fp32 row norms.
    __bf16* xb = (__bf16*)d_ws;
    float* sq  = (float*)((char*)d_ws + (size_t)N * D * sizeof(__bf16));

    prep_kernel<<<N / 4, 256, 0, stream>>>(x, xb, sq);

    int nblocks = NB * (NB + 1) / 2;  // 528 lower-triangular block pairs
    pairdist_kernel<<<nblocks, 256, 0, stream>>>(xb, sq, out);
}